// Round 1
// baseline (785.811 us; speedup 1.0000x reference)
//
#include <hip/hip_runtime.h>
#include <hip/hip_bf16.h>
#include <math.h>

#define SORT_BLOCK 256
#define SORT_IPT   16
#define SORT_TILE  (SORT_BLOCK * SORT_IPT)   // 4096
#define RADIX_BINS 16
#define RADIX_PASSES 8

// ---------------- key generation ----------------
__global__ __launch_bounds__(256) void k_keys(const float* __restrict__ pts,
                                              const float* __restrict__ w2v,
                                              int N,
                                              unsigned* __restrict__ keys,
                                              unsigned* __restrict__ idx)
{
    int i = blockIdx.x * 256 + threadIdx.x;
    if (i >= N) return;
    float x = pts[3*i+0], y = pts[3*i+1], z = pts[3*i+2];
    float zv = x*w2v[2] + y*w2v[6] + z*w2v[10] + w2v[14];
    float key = (zv >= 0.2f) ? zv : __int_as_float(0x7f800000); // +inf when culled
    unsigned u = __float_as_uint(key);
    u ^= (u & 0x80000000u) ? 0xFFFFFFFFu : 0x80000000u;        // float -> sortable u32
    keys[i] = u;
    idx[i]  = (unsigned)i;
}

// ---------------- per-tile digit histogram (digit-major layout) ----------------
__global__ __launch_bounds__(256) void k_hist(const unsigned* __restrict__ keys,
                                              int N, int numTiles, int shift,
                                              unsigned* __restrict__ hist)
{
    __shared__ unsigned bins[RADIX_BINS];
    int t = threadIdx.x, b = blockIdx.x;
    if (t < RADIX_BINS) bins[t] = 0;
    __syncthreads();
    int base = b * SORT_TILE;
    for (int k = 0; k < SORT_IPT; ++k) {
        int l = base + k * SORT_BLOCK + t;
        if (l < N) atomicAdd(&bins[(keys[l] >> shift) & (RADIX_BINS - 1)], 1u);
    }
    __syncthreads();
    if (t < RADIX_BINS) hist[t * numTiles + b] = bins[t];
}

// ---------------- exclusive scan over hist (E = 16*numTiles, small) ----------------
__global__ __launch_bounds__(256) void k_scan(unsigned* __restrict__ hist, int E)
{
    __shared__ unsigned sums[256];
    int t = threadIdx.x;
    int per = (E + 255) / 256;
    int s = t * per;
    int e = s + per; if (e > E) e = E; if (s > E) s = E;
    unsigned acc = 0;
    for (int i = s; i < e; ++i) acc += hist[i];
    sums[t] = acc;
    __syncthreads();
    for (int off = 1; off < 256; off <<= 1) {
        unsigned v = (t >= off) ? sums[t - off] : 0u;
        __syncthreads();
        sums[t] += v;
        __syncthreads();
    }
    unsigned run = (t == 0) ? 0u : sums[t - 1];
    for (int i = s; i < e; ++i) { unsigned h = hist[i]; hist[i] = run; run += h; }
}

// ---------------- stable rank + scatter ----------------
__global__ __launch_bounds__(256) void k_scatter(const unsigned* __restrict__ keys,
                                                 const unsigned* __restrict__ vals,
                                                 int N, int numTiles, int shift,
                                                 const unsigned* __restrict__ hist,
                                                 unsigned* __restrict__ okeys,
                                                 unsigned* __restrict__ ovals)
{
    __shared__ unsigned short cnt[RADIX_BINS * SORT_BLOCK];  // [d*256 + t]
    __shared__ unsigned       digBase[RADIX_BINS];
    __shared__ unsigned short digStart[RADIX_BINS];
    __shared__ unsigned       tsum[SORT_BLOCK];

    int t = threadIdx.x, b = blockIdx.x;
    int base   = b * SORT_TILE;
    int myBase = base + t * SORT_IPT;
    int nv = N - myBase; if (nv < 0) nv = 0; if (nv > SORT_IPT) nv = SORT_IPT;

    // zero my counter column (only this thread touches it before the barrier)
    for (int d = 0; d < RADIX_BINS; ++d) cnt[d * SORT_BLOCK + t] = 0;

    unsigned k_[SORT_IPT], v_[SORT_IPT];
    unsigned short rank_[SORT_IPT];
    if (nv == SORT_IPT) {   // vectorized contiguous load, 64B/thread
        const uint4* kp = (const uint4*)(keys + myBase);
        const uint4* vp = (const uint4*)(vals + myBase);
        #pragma unroll
        for (int q = 0; q < SORT_IPT / 4; ++q) {
            uint4 kv = kp[q], vv = vp[q];
            k_[4*q+0]=kv.x; k_[4*q+1]=kv.y; k_[4*q+2]=kv.z; k_[4*q+3]=kv.w;
            v_[4*q+0]=vv.x; v_[4*q+1]=vv.y; v_[4*q+2]=vv.z; v_[4*q+3]=vv.w;
        }
    } else {
        for (int k = 0; k < nv; ++k) { k_[k] = keys[myBase + k]; v_[k] = vals[myBase + k]; }
    }

    // sequential (stable) per-thread ranking
    for (int k = 0; k < nv; ++k) {
        unsigned d = (k_[k] >> shift) & (RADIX_BINS - 1);
        rank_[k] = cnt[d * SORT_BLOCK + t]++;
    }
    __syncthreads();

    // exclusive scan over the 4096 u16 counters, flatten f = d*256 + t
    {
        int f0 = t * 16;
        unsigned acc = 0;
        #pragma unroll
        for (int j = 0; j < 16; ++j) acc += cnt[f0 + j];
        tsum[t] = acc;
        __syncthreads();
        for (int off = 1; off < 256; off <<= 1) {
            unsigned v = (t >= off) ? tsum[t - off] : 0u;
            __syncthreads();
            tsum[t] += v;
            __syncthreads();
        }
        unsigned run = (t == 0) ? 0u : tsum[t - 1];
        #pragma unroll
        for (int j = 0; j < 16; ++j) {
            unsigned h = cnt[f0 + j];
            cnt[f0 + j] = (unsigned short)run;
            run += h;
        }
    }
    __syncthreads();
    if (t < RADIX_BINS) {
        digBase[t]  = hist[t * numTiles + b];
        digStart[t] = cnt[t * SORT_BLOCK];
    }
    __syncthreads();

    for (int k = 0; k < nv; ++k) {
        unsigned d = (k_[k] >> shift) & (RADIX_BINS - 1);
        unsigned pos = digBase[d]
                     + (unsigned)(cnt[d * SORT_BLOCK + t] - digStart[d])
                     + (unsigned)rank_[k];
        okeys[pos] = k_[k];
        ovals[pos] = v_[k];
    }
}

// ---------------- full per-point math, emitted in sorted order ----------------
__global__ __launch_bounds__(256) void k_emit(const unsigned* __restrict__ order,
                                              const float* __restrict__ pts,
                                              const float* __restrict__ cols,
                                              const float* __restrict__ opa,
                                              const float* __restrict__ scl,
                                              const float* __restrict__ qt,
                                              const float* __restrict__ w2v,
                                              const float* __restrict__ fpm,
                                              const float* __restrict__ tanx_p,
                                              const float* __restrict__ tany_p,
                                              const float* __restrict__ fx_p,
                                              const float* __restrict__ fy_p,
                                              const int* __restrict__ wp,
                                              const int* __restrict__ hp,
                                              float* __restrict__ out, int N)
{
    __shared__ float srow[256 * 21];
    int i = blockIdx.x * 256 + threadIdx.x;
    if (i < N) {
        int j = (int)order[i];
        float x = pts[3*j+0], y = pts[3*j+1], z = pts[3*j+2];

        // quaternion -> rotation
        float qw = qt[4*j+0], qx = qt[4*j+1], qy = qt[4*j+2], qz = qt[4*j+3];
        float qn = sqrtf(qw*qw + qx*qx + qy*qy + qz*qz);
        qw /= qn; qx /= qn; qy /= qn; qz /= qn;
        float R00 = 1.f - 2.f*(qy*qy + qz*qz), R01 = 2.f*(qx*qy - qw*qz), R02 = 2.f*(qx*qz + qw*qy);
        float R10 = 2.f*(qx*qy + qw*qz), R11 = 1.f - 2.f*(qx*qx + qz*qz), R12 = 2.f*(qy*qz - qw*qx);
        float R20 = 2.f*(qx*qz - qw*qy), R21 = 2.f*(qy*qz + qw*qx), R22 = 1.f - 2.f*(qx*qx + qy*qy);

        float s0 = scl[3*j+0], s1 = scl[3*j+1], s2 = scl[3*j+2];
        float M00=R00*s0, M01=R01*s1, M02=R02*s2;
        float M10=R10*s0, M11=R11*s1, M12=R12*s2;
        float M20=R20*s0, M21=R21*s1, M22=R22*s2;
        float C00=M00*M00+M01*M01+M02*M02;
        float C01=M00*M10+M01*M11+M02*M12;
        float C02=M00*M20+M01*M21+M02*M22;
        float C11=M10*M10+M11*M11+M12*M12;
        float C12=M10*M20+M11*M21+M12*M22;
        float C22=M20*M20+M21*M21+M22*M22;

        float pvx = x*w2v[0] + y*w2v[4] + z*w2v[8]  + w2v[12];
        float pvy = x*w2v[1] + y*w2v[5] + z*w2v[9]  + w2v[13];
        float zv  = x*w2v[2] + y*w2v[6] + z*w2v[10] + w2v[14];
        bool in_view = (zv >= 0.2f);

        float cx = x*fpm[0] + y*fpm[4] + z*fpm[8]  + fpm[12];
        float cy = x*fpm[1] + y*fpm[5] + z*fpm[9]  + fpm[13];
        float cw = x*fpm[3] + y*fpm[7] + z*fpm[11] + fpm[15];
        float ndx = cx / cw, ndy = cy / cw;
        float Wf = (float)wp[0], Hf = (float)hp[0];
        float px = ((ndx + 1.f) * Wf - 1.f) * 0.5f;
        float py = ((ndy + 1.f) * Hf - 1.f) * 0.5f;

        float tanX = tanx_p[0], tanY = tany_p[0], fx = fx_p[0], fy = fy_p[0];
        float lx = 1.3f * tanX, ly = 1.3f * tanY;
        float xc = fminf(fmaxf(pvx / zv, -lx), lx) * zv;
        float yc = fminf(fmaxf(pvy / zv, -ly), ly) * zv;
        float z2 = zv * zv;
        float J00 = fx / zv, J02 = -(fx * xc) / z2;
        float J11 = fy / zv, J12 = -(fy * yc) / z2;

        // T = J @ W^T (rows 0,1); W^T[j][k] = w2v[k*4+j]
        float T00 = J00*w2v[0] + J02*w2v[2];
        float T01 = J00*w2v[4] + J02*w2v[6];
        float T02 = J00*w2v[8] + J02*w2v[10];
        float T10 = J11*w2v[1] + J12*w2v[2];
        float T11 = J11*w2v[5] + J12*w2v[6];
        float T12 = J11*w2v[9] + J12*w2v[10];

        float V00 = T00*C00 + T01*C01 + T02*C02;
        float V01 = T00*C01 + T01*C11 + T02*C12;
        float V02 = T00*C02 + T01*C12 + T02*C22;
        float V10 = T10*C00 + T11*C01 + T12*C02;
        float V11 = T10*C01 + T11*C11 + T12*C12;
        float V12 = T10*C02 + T11*C12 + T12*C22;
        float c00 = V00*T00 + V01*T01 + V02*T02;
        float c01 = V00*T10 + V01*T11 + V02*T12;
        float c10 = V10*T00 + V11*T01 + V12*T02;
        float c11 = V10*T10 + V11*T11 + V12*T12;

        float det = c00*c11 - c01*c10;
        float det_safe = (fabsf(det) < 1e-6f) ? 1e-6f : det;
        float i00 =  c11 / det_safe, i01 = -c01 / det_safe;
        float i10 = -c10 / det_safe, i11 =  c00 / det_safe;
        float mid = 0.5f * (c00 + c11);
        float inter = fmaxf(mid*mid - det, 0.1f);
        float lam = mid + sqrtf(inter);
        float radius = ceilf(3.0f * sqrtf(fmaxf(lam, 0.0f)));
        float min_x = floorf(px - radius), min_y = floorf(py - radius);
        float max_x = ceilf(px + radius),  max_y = ceilf(py + radius);
        float op = 1.0f / (1.0f + expf(-opa[j]));

        float* r = &srow[threadIdx.x * 21];
        r[0]=px; r[1]=py; r[2]=zv;
        r[3]=c00; r[4]=c01; r[5]=c10; r[6]=c11;
        r[7]=i00; r[8]=i01; r[9]=i10; r[10]=i11;
        r[11]=radius; r[12]=min_x; r[13]=min_y; r[14]=max_x; r[15]=max_y;
        r[16]=cols[3*j+0]; r[17]=cols[3*j+1]; r[18]=cols[3*j+2];
        r[19]=op; r[20]= in_view ? 1.0f : 0.0f;
    }
    __syncthreads();
    int blockBase = blockIdx.x * 256;
    int valid = N - blockBase; if (valid > 256) valid = 256;
    if (valid > 0) {
        float* dst = out + (size_t)blockBase * 21;
        for (int u = threadIdx.x; u < valid * 21; u += 256) dst[u] = srow[u];
    }
}

extern "C" void kernel_launch(void* const* d_in, const int* in_sizes, int n_in,
                              void* d_out, int out_size, void* d_ws, size_t ws_size,
                              hipStream_t stream)
{
    const float* pts  = (const float*)d_in[0];
    const float* cols = (const float*)d_in[1];
    const float* opa  = (const float*)d_in[2];
    const float* scl  = (const float*)d_in[3];
    const float* qt   = (const float*)d_in[4];
    const float* w2v  = (const float*)d_in[5];
    const float* fpm  = (const float*)d_in[6];
    const float* tanx = (const float*)d_in[7];
    const float* tany = (const float*)d_in[8];
    const float* fx   = (const float*)d_in[9];
    const float* fy   = (const float*)d_in[10];
    const int*   wp   = (const int*)d_in[11];
    const int*   hp   = (const int*)d_in[12];

    int N = in_sizes[0] / 3;
    int numTiles = (N + SORT_TILE - 1) / SORT_TILE;

    unsigned* keysA = (unsigned*)d_ws;
    unsigned* idxA  = keysA + N;
    unsigned* keysB = idxA  + N;
    unsigned* idxB  = keysB + N;
    unsigned* hist  = idxB  + N;   // RADIX_BINS * numTiles entries

    int nb = (N + 255) / 256;
    k_keys<<<nb, 256, 0, stream>>>(pts, w2v, N, keysA, idxA);

    unsigned *ck = keysA, *cv = idxA, *nk = keysB, *nvv = idxB;
    for (int p = 0; p < RADIX_PASSES; ++p) {
        int shift = p * 4;
        k_hist<<<numTiles, 256, 0, stream>>>(ck, N, numTiles, shift, hist);
        k_scan<<<1, 256, 0, stream>>>(hist, RADIX_BINS * numTiles);
        k_scatter<<<numTiles, 256, 0, stream>>>(ck, cv, N, numTiles, shift, hist, nk, nvv);
        unsigned* tk = ck; ck = nk; nk = tk;
        unsigned* tv = cv; cv = nvv; nvv = tv;
    }

    k_emit<<<nb, 256, 0, stream>>>(cv, pts, cols, opa, scl, qt, w2v, fpm,
                                   tanx, tany, fx, fy, wp, hp,
                                   (float*)d_out, N);
}